// Round 15
// baseline (49.089 us; speedup 1.0000x reference)
//
#include <hip/hip_runtime.h>
#include <hip/hip_bf16.h>
#include <stdint.h>

#define NB    16
#define CIN   2048
#define OUTC  256
#define HW    1024
#define BJ    64
#define BK    64
#define NJT   (HW / BJ)         // 16 j-tiles
#define NKS   2                 // K split factor
#define KSL   (CIN / BK / NKS)  // 16 local K-steps per block
#define NPART (NKS * NB * NJT)  // 512 partial sets

typedef __attribute__((ext_vector_type(8))) short bf16x8;
typedef __attribute__((ext_vector_type(4))) float f32x4;
typedef __attribute__((ext_vector_type(4))) unsigned int u32x4;

__device__ __forceinline__ unsigned int f2bf(float f) {
    union { float f; unsigned int u; } a; a.f = f;
    return (a.u + 0x7FFFu + ((a.u >> 16) & 1u)) >> 16;  // RNE
}

// Raw barrier: drains LDS ops only; global prefetch loads stay in flight.
__device__ __forceinline__ void block_sync_lds() {
    asm volatile("s_waitcnt lgkmcnt(0)" ::: "memory");
    __builtin_amdgcn_s_barrier();
    asm volatile("" ::: "memory");
}

// ---- kernel 1: W fp32 -> bf16 A-fragments in MFMA lane order. ----
__global__ void wprep_kernel(const float* __restrict__ W, unsigned short* __restrict__ Afrag) {
    int g  = blockIdx.x * blockDim.x + threadIdx.x;   // 65536
    int o  = g >> 8;
    int kc = g & 255;          // 8-k chunk within row
    const float4* p = reinterpret_cast<const float4*>(W + o * CIN + kc * 8);
    float4 v0 = p[0], v1 = p[1];
    u32x4 pk;
    pk.x = f2bf(v0.x) | (f2bf(v0.y) << 16);
    pk.y = f2bf(v0.z) | (f2bf(v0.w) << 16);
    pk.z = f2bf(v1.x) | (f2bf(v1.y) << 16);
    pk.w = f2bf(v1.z) | (f2bf(v1.w) << 16);
    int ks32 = kc >> 2, g8 = kc & 3;
    int lane = g8 * 16 + (o & 15), ot = o >> 4;
    *reinterpret_cast<u32x4*>(Afrag + (((size_t)ks32 * 16 + ot) * 64 + lane) * 8) = pk;
}

// ---- kernel 2: 4-wave GEMM, wave-tile 64o x 64j (32 MFMA per wave-step),
//      K-split x2 -> 512 blocks = 2 decorrelated barrier domains per CU.
//      B LDS fragment-linear conflict-free; A direct from L2 fragments.
__global__ __launch_bounds__(256, 2) void gemm_stats_kernel(
    const float* __restrict__ x,             // [16][2048][1024]
    const unsigned short* __restrict__ Afrag,
    float* __restrict__ s1_part,             // [NPART][OUTC]
    float* __restrict__ s2_part)             // [NPART][OUTC]
{
    __shared__ __align__(16) unsigned short B0[4096], B1[4096]; // 8 KB each (64j x 64k)

    const int tid    = threadIdx.x;
    const int lane   = tid & 63;
    const int wave   = tid >> 6;          // 0..3; wave's o-rows = [64w, 64w+64)
    const int blk    = blockIdx.x;        // 0..511: kslice*256 + n*16 + jt
    const int kslice = blk >> 8;
    const int n      = (blk >> 4) & 15;
    const int jt     = blk & 15;
    const int j0     = jt * BJ;

    const float* xn = x + (size_t)n * CIN * HW + (size_t)kslice * (CIN / NKS) * HW;

    // B staging: thread (bj = tid&63, kq = wave) loads 16 floats:
    // k = kq*8+i and k = 32+kq*8+i -> two ds_write_b128 at fragment slots.
    const int bj = tid & 63;
    const int kq = tid >> 6;              // 0..3
    const float* Bgp = xn + (size_t)(kq * 8) * HW + j0 + bj;
    const int offB = (bj >> 4) * 512 + kq * 128 + (bj & 15) * 8;  // h=0; h=1 at +2048

    const int rbase = lane * 8;    // fragment-linear read base (+ h*2048 + ni*512)
    const unsigned short* Ab = Afrag
        + (size_t)kslice * (KSL * 2 * 16 * 64 * 8) + (size_t)lane * 8;

#define CLMP(v) (((v) < KSL) ? (v) : KSL - 1)
#define LDA(ks, R) { _Pragma("unroll") \
    for (int h = 0; h < 2; ++h) _Pragma("unroll") for (int mi = 0; mi < 4; ++mi) \
        R[h * 4 + mi] = *(const u32x4*)(Ab + ((((ks) * 2 + h) * 16 + wave * 4 + mi) * 64) * 8); }
#define LDB(ks, F) { const float* p = Bgp + (size_t)(ks) * BK * HW; \
    _Pragma("unroll") for (int i = 0; i < 8; ++i) F[i] = p[(size_t)i * HW]; \
    _Pragma("unroll") for (int i = 0; i < 8; ++i) F[8 + i] = p[(size_t)(32 + i) * HW]; }
#define WRITEB(Bb, F) { u32x4 pk; \
    pk.x = f2bf(F[0]) | (f2bf(F[1]) << 16); pk.y = f2bf(F[2]) | (f2bf(F[3]) << 16); \
    pk.z = f2bf(F[4]) | (f2bf(F[5]) << 16); pk.w = f2bf(F[6]) | (f2bf(F[7]) << 16); \
    *(u32x4*)&Bb[offB] = pk; \
    pk.x = f2bf(F[8]) | (f2bf(F[9]) << 16);   pk.y = f2bf(F[10]) | (f2bf(F[11]) << 16); \
    pk.z = f2bf(F[12]) | (f2bf(F[13]) << 16); pk.w = f2bf(F[14]) | (f2bf(F[15]) << 16); \
    *(u32x4*)&Bb[offB + 2048] = pk; }
#define COMPUTE(Bb, R) { _Pragma("unroll") \
    for (int h = 0; h < 2; ++h) _Pragma("unroll") for (int ni = 0; ni < 4; ++ni) { \
        bf16x8 bf = *(const bf16x8*)&Bb[h * 2048 + ni * 512 + rbase]; \
        _Pragma("unroll") \
        for (int mi = 0; mi < 4; ++mi) { \
            bf16x8 af = *(const bf16x8*)&R[h * 4 + mi]; \
            acc[mi][ni] = __builtin_amdgcn_mfma_f32_16x16x32_bf16(af, bf, acc[mi][ni], 0, 0, 0); \
    } } }

    f32x4 acc[4][4] = {};
    u32x4 Aa0[8], Aa1[8];      // A reg sets: Aa0 <-> even steps (B0), Aa1 <-> odd (B1)
    float BsA[16], BsB[16];

    LDA(0, Aa0); LDB(0, BsA);
    LDA(1, Aa1); LDB(1, BsB);
    WRITEB(B0, BsA);
    LDB(2, BsA);
    block_sync_lds();

    #pragma unroll 1
    for (int ks = 0; ks < KSL; ks += 2) {
        // even step: compute B0 / Aa0
        COMPUTE(B0, Aa0);
        {
            LDA(CLMP(ks + 2), Aa0);
            WRITEB(B1, BsB);               // stage data ks+1
            LDB(CLMP(ks + 3), BsB);
            block_sync_lds();
        }
        // odd step: compute B1 / Aa1
        COMPUTE(B1, Aa1);
        {
            LDA(CLMP(ks + 3), Aa1);
        }
        if (ks + 2 < KSL) {
            WRITEB(B0, BsA);               // stage data ks+2
            LDB(CLMP(ks + 4), BsA);
            block_sync_lds();
        }
    }

    // ---- epilogue: per-channel sum / sum-of-squares over this block's 64 j ----
    // C/D layout: col(j) = lane&15, row = (lane>>4)*4 + r  [m89]
    float rs[4][4], rq[4][4];
    #pragma unroll
    for (int mi = 0; mi < 4; ++mi)
        #pragma unroll
        for (int r = 0; r < 4; ++r) {
            float s = 0.f, q = 0.f;
            #pragma unroll
            for (int ni = 0; ni < 4; ++ni) {
                float v = acc[mi][ni][r];
                s += v; q += v * v;
            }
            rs[mi][r] = s; rq[mi][r] = q;
        }
    #pragma unroll
    for (int m = 1; m < 16; m <<= 1)
        #pragma unroll
        for (int mi = 0; mi < 4; ++mi)
            #pragma unroll
            for (int r = 0; r < 4; ++r) {
                rs[mi][r] += __shfl_xor(rs[mi][r], m, 64);
                rq[mi][r] += __shfl_xor(rq[mi][r], m, 64);
            }
    if ((lane & 15) == 0) {
        const int gK = lane >> 4;
        #pragma unroll
        for (int mi = 0; mi < 4; ++mi)
            #pragma unroll
            for (int r = 0; r < 4; ++r) {
                int o = wave * 64 + mi * 16 + gK * 4 + r;
                s1_part[(size_t)blk * OUTC + o] = rs[mi][r];
                s2_part[(size_t)blk * OUTC + o] = rq[mi][r];
            }
    }
#undef CLMP
#undef LDA
#undef LDB
#undef WRITEB
#undef COMPUTE
}

// ---- kernel 3 (fused finalize+broadcast): block = (n, 16 channels).
//      Partials indexed blk = kslice*256 + n*16 + jt (512 sets).
__global__ __launch_bounds__(256) void finalize_bcast_kernel(
    const float* __restrict__ s1_part,   // [NPART][OUTC]
    const float* __restrict__ s2_part,   // [NPART][OUTC]
    const float* __restrict__ gamma,
    const float* __restrict__ beta,
    float* __restrict__ out)             // [NB][OUTC][1024]
{
    const int tid   = threadIdx.x;
    const int slice = tid & 15;          // jt-slice
    const int o_l   = tid >> 4;
    const int n0    = blockIdx.x >> 4;
    const int o     = (blockIdx.x & 15) * 16 + o_l;

    float S1 = 0.f, S2 = 0.f;
    #pragma unroll
    for (int q = 0; q < 32; ++q) {
        int p = slice * 32 + q;          // covers all 512 partials
        S1 += s1_part[p * OUTC + o];
        S2 += s2_part[p * OUTC + o];
    }
    // this block's n: sum over kslice(2) at jt = slice
    float s1n = s1_part[((0 * NB + n0) * NJT + slice) * OUTC + o]
              + s1_part[((1 * NB + n0) * NJT + slice) * OUTC + o];
    #pragma unroll
    for (int m = 1; m < 16; m <<= 1) {
        S1  += __shfl_xor(S1, m, 64);
        S2  += __shfl_xor(S2, m, 64);
        s1n += __shfl_xor(s1n, m, 64);
    }
    float mean = S1 * (1.f / 16384.f);
    float var  = S2 * (1.f / 16384.f) - mean * mean;   // biased var (matches ref)
    float inv  = rsqrtf(var + 1e-5f);
    float v = gamma[o] * (s1n * (1.f / 1024.f) - mean) * inv + beta[o];

    float4 vv = make_float4(v, v, v, v);
    float4* dst = reinterpret_cast<float4*>(out + ((size_t)(n0 * OUTC + o)) * HW);
    #pragma unroll
    for (int it = 0; it < 16; ++it)
        dst[it * 16 + slice] = vv;
}

extern "C" void kernel_launch(void* const* d_in, const int* in_sizes, int n_in,
                              void* d_out, int out_size, void* d_ws, size_t ws_size,
                              hipStream_t stream) {
    const float* x     = (const float*)d_in[0];
    const float* W     = (const float*)d_in[1];
    const float* gamma = (const float*)d_in[2];
    const float* beta  = (const float*)d_in[3];
    float* out = (float*)d_out;

    char* ws = (char*)d_ws;
    unsigned short* Afrag = (unsigned short*)ws;                 // 1 MiB
    float* s1_part = (float*)(ws + (1 << 20));                   // 512 KB
    float* s2_part = (float*)(ws + (1 << 20) + (512 << 10));     // 512 KB

    hipLaunchKernelGGL(wprep_kernel, dim3(256), dim3(256), 0, stream, W, Afrag);
    hipLaunchKernelGGL(gemm_stats_kernel, dim3(NPART), dim3(256), 0, stream,
                       x, Afrag, s1_part, s2_part);
    hipLaunchKernelGGL(finalize_bcast_kernel, dim3(NB * (OUTC / 16)), dim3(256), 0, stream,
                       s1_part, s2_part, gamma, beta, out);
}